// Round 1
// baseline (238.439 us; speedup 1.0000x reference)
//
#include <hip/hip_runtime.h>
#include <hip/hip_bf16.h>

#define NB 4
#define NH 16
#define NBH 64
#define NSEQ 2048
#define DD 128
#define EPS 1e-6f

typedef __bf16 bf16x8 __attribute__((ext_vector_type(8)));
typedef __bf16 bf16x4 __attribute__((ext_vector_type(4)));
typedef float  f32x4  __attribute__((ext_vector_type(4)));

__device__ __forceinline__ float elu1(float x) {
    // elu(x)+1 = x+1 (x>0), exp(x) (x<=0)
    return x > 0.f ? x + 1.f : __expf(x);
}

// ---------------------------------------------------------------------------
// Phase 1: partial KV^T.  grid (8, 64) = (n-chunk of 256 rows, bh), 512 thr.
// part[(bh*8+s)][e][d] = sum over chunk rows n of Vf[n,e]*Kf[n,d]   (fp32)
// LDS: KfT[d][n], VfT[e][n], both 128 x 64 (stride 72), bf16, per 64-row sub.
// ---------------------------------------------------------------------------
__global__ __launch_bounds__(512) void kv_partial_kernel(
    const float* __restrict__ K, const float* __restrict__ V,
    const float* __restrict__ mask, float* __restrict__ part)
{
    __shared__ __bf16 KfT[128 * 72];
    __shared__ __bf16 VfT[128 * 72];
    __shared__ float  mloc[256];

    const int s  = blockIdx.x;   // n-chunk
    const int bh = blockIdx.y;
    const int b  = bh >> 4;
    const int t  = threadIdx.x;
    const int n0 = s * 256;

    if (t < 256) mloc[t] = mask[b * NSEQ + n0 + t];

    const int d    = t & 127;     // staging: column this thread handles
    const int qtr  = t >> 7;      // staging: row group 0..3
    const int lane = t & 63;
    const int w    = t >> 6;      // wave 0..7
    const int quad = lane >> 4;
    const int col  = lane & 15;

    f32x4 acc[8];
    #pragma unroll
    for (int nt = 0; nt < 8; ++nt) acc[nt] = (f32x4){0.f, 0.f, 0.f, 0.f};

    const float* Kb = K + ((size_t)bh * NSEQ + n0) * DD;
    const float* Vb = V + ((size_t)bh * NSEQ + n0) * DD;

    for (int sub = 0; sub < 4; ++sub) {
        __syncthreads();   // previous MFMA reads done before restaging
        // stage 64 seq rows (this thread: 16 rows, fixed column d)
        #pragma unroll
        for (int r0 = 0; r0 < 16; r0 += 4) {
            bf16x4 kp, vp;
            #pragma unroll
            for (int j = 0; j < 4; ++j) {
                int nl = sub * 64 + qtr * 16 + r0 + j;   // row within 256-chunk
                float m  = mloc[nl];
                float kx = Kb[(size_t)nl * DD + d];
                float vx = Vb[(size_t)nl * DD + d];
                kp[j] = (__bf16)(elu1(kx) * m);
                vp[j] = (__bf16)(vx * m);
            }
            int nn = qtr * 16 + r0;                      // column in sub-buffer
            *(bf16x4*)&KfT[d * 72 + nn] = kp;
            *(bf16x4*)&VfT[d * 72 + nn] = vp;            // e == d role for V
        }
        __syncthreads();

        // MFMA: C[e][d] += VfT(e,k) * KfT(d,k), k = 64 rows -> 2 ksteps of 32
        #pragma unroll
        for (int kk = 0; kk < 2; ++kk) {
            int k0 = kk * 32 + quad * 8;
            bf16x8 a = *(bf16x8*)&VfT[(w * 16 + col) * 72 + k0];
            #pragma unroll
            for (int nt = 0; nt < 8; ++nt) {
                bf16x8 bb = *(bf16x8*)&KfT[(nt * 16 + col) * 72 + k0];
                acc[nt] = __builtin_amdgcn_mfma_f32_16x16x32_bf16(a, bb, acc[nt], 0, 0, 0);
            }
        }
    }

    // store partial KV^T (fp32), layout [e][d]
    float* po = part + (((size_t)bh * 8 + s) << 14);
    #pragma unroll
    for (int r = 0; r < 4; ++r) {
        int e = w * 16 + quad * 4 + r;
        #pragma unroll
        for (int nt = 0; nt < 8; ++nt)
            po[e * 128 + nt * 16 + col] = acc[nt][r];
    }
}

// ---------------------------------------------------------------------------
// Phase 2: sum 8 partials -> bf16 KVT[bh][e][d].  262144 threads, 4 elems ea.
// ---------------------------------------------------------------------------
__global__ __launch_bounds__(256) void kv_reduce_kernel(
    const float* __restrict__ part, __bf16* __restrict__ kvt)
{
    int gid = blockIdx.x * 256 + threadIdx.x;   // 0..262143
    int i   = gid * 4;
    int bh  = i >> 14;
    int ii  = i & 16383;
    const float* p = part + (((size_t)bh * 8) << 14) + ii;
    f32x4 sum = (f32x4){0.f, 0.f, 0.f, 0.f};
    #pragma unroll
    for (int s = 0; s < 8; ++s)
        sum += *(const f32x4*)(p + ((size_t)s << 14));
    bf16x4 o;
    o[0] = (__bf16)sum[0]; o[1] = (__bf16)sum[1];
    o[2] = (__bf16)sum[2]; o[3] = (__bf16)sum[3];
    *(bf16x4*)&kvt[i] = o;
}

// ---------------------------------------------------------------------------
// Phase 3: out = rmsnorm( Qf @ KV ).  grid (32, 64) = (64-row chunk, bh), 256 thr.
// A = Qf rows (natural layout), B(k=d, n=e) = KVT[e][d] (natural given KVT).
// ---------------------------------------------------------------------------
__global__ __launch_bounds__(256) void qkv_norm_kernel(
    const float* __restrict__ Q, const __bf16* __restrict__ kvt,
    float* __restrict__ out)
{
    __shared__ __bf16 KVT[128 * 136];
    __shared__ __bf16 Qf[64 * 136];

    const int bh   = blockIdx.y;
    const int row0 = blockIdx.x * 64;
    const int t    = threadIdx.x;
    const int lane = t & 63;
    const int w    = t >> 6;     // wave 0..3 -> rows [w*16, +16)
    const int quad = lane >> 4;
    const int col  = lane & 15;

    // stage KVT (bf16, 128x128) into padded LDS
    {
        const __bf16* src = kvt + ((size_t)bh << 14);
        #pragma unroll
        for (int i = 0; i < 8; ++i) {
            int idx = i * 256 + t;
            int e   = idx >> 4;
            int dd  = (idx & 15) * 8;
            *(bf16x8*)&KVT[e * 136 + dd] = *(const bf16x8*)&src[e * 128 + dd];
        }
    }
    // stage Qf = elu(Q)+1 (bf16, 64x128)
    {
        const float* Qb = Q + ((size_t)bh * NSEQ + row0) * DD;
        #pragma unroll
        for (int i = 0; i < 8; ++i) {
            int idx = i * 256 + t;
            int r   = idx >> 5;
            int dd  = (idx & 31) * 4;
            f32x4 q = *(const f32x4*)&Qb[r * DD + dd];
            bf16x4 qq;
            qq[0] = (__bf16)elu1(q[0]); qq[1] = (__bf16)elu1(q[1]);
            qq[2] = (__bf16)elu1(q[2]); qq[3] = (__bf16)elu1(q[3]);
            *(bf16x4*)&Qf[r * 136 + dd] = qq;
        }
    }
    __syncthreads();

    f32x4 acc[8];
    #pragma unroll
    for (int et = 0; et < 8; ++et) acc[et] = (f32x4){0.f, 0.f, 0.f, 0.f};

    #pragma unroll
    for (int kk = 0; kk < 4; ++kk) {
        int k0 = kk * 32 + quad * 8;
        bf16x8 a = *(bf16x8*)&Qf[(w * 16 + col) * 136 + k0];
        #pragma unroll
        for (int et = 0; et < 8; ++et) {
            bf16x8 bb = *(bf16x8*)&KVT[(et * 16 + col) * 136 + k0];
            acc[et] = __builtin_amdgcn_mfma_f32_16x16x32_bf16(a, bb, acc[et], 0, 0, 0);
        }
    }

    // RMS norm per row + store.  C layout: row = quad*4+reg, col = lane&15.
    float* ob = out + ((size_t)bh * NSEQ + row0) * DD;
    #pragma unroll
    for (int r = 0; r < 4; ++r) {
        float p = 0.f;
        #pragma unroll
        for (int et = 0; et < 8; ++et) p += acc[et][r] * acc[et][r];
        p += __shfl_xor(p, 1);
        p += __shfl_xor(p, 2);
        p += __shfl_xor(p, 4);
        p += __shfl_xor(p, 8);   // sum over the 16 lanes holding this row
        float scale = rsqrtf(p * (1.0f / 128.0f) + EPS);
        int row = w * 16 + quad * 4 + r;
        #pragma unroll
        for (int et = 0; et < 8; ++et)
            ob[row * DD + et * 16 + col] = acc[et][r] * scale;
    }
}

extern "C" void kernel_launch(void* const* d_in, const int* in_sizes, int n_in,
                              void* d_out, int out_size, void* d_ws, size_t ws_size,
                              hipStream_t stream) {
    const float* Q    = (const float*)d_in[0];
    const float* K    = (const float*)d_in[1];
    const float* V    = (const float*)d_in[2];
    const float* mask = (const float*)d_in[3];
    float* out = (float*)d_out;

    float*  part = (float*)d_ws;                                   // 32 MB
    __bf16* kvt  = (__bf16*)((char*)d_ws + (size_t)NBH * 8 * 16384 * 4);

    kv_partial_kernel<<<dim3(8, NBH), 512, 0, stream>>>(K, V, mask, part);
    kv_reduce_kernel<<<1024, 256, 0, stream>>>(part, kvt);
    qkv_norm_kernel<<<dim3(32, NBH), 256, 0, stream>>>(Q, kvt, out);
}